// Round 1
// baseline (1576.285 us; speedup 1.0000x reference)
//
#include <hip/hip_runtime.h>
#include <cstdint>
#include <cstddef>

#define HID 1024
#define EMBED 512
#define VOCABSZ 50257
#define MAXLEN 1024
#define BATCH 64
#define ATTNSZ 1024
#define MTOT (MAXLEN * BATCH)
#define GATE3 (3 * HID)

typedef __attribute__((ext_vector_type(8))) short s16x8;
typedef __attribute__((ext_vector_type(4))) float f32x4;
typedef __attribute__((ext_vector_type(4))) unsigned short u16x4;

static __device__ __forceinline__ unsigned short f2bf(float f) {
  union { float fv; unsigned int u; } v; v.fv = f;
  unsigned int u = v.u;
  u += 0x7fffu + ((u >> 16) & 1u);   // RNE
  return (unsigned short)(u >> 16);
}

static __device__ __forceinline__ float fast_tanh(float x) {
  x = fminf(fmaxf(x, -15.f), 15.f);
  float t = __expf(2.f * x);
  return (t - 1.f) / (t + 1.f);
}

static __device__ __forceinline__ float fast_sigmoid(float x) {
  return 1.f / (1.f + __expf(-x));
}

// ---------------------------------------------------------------------------
// K0: w1_e (rows 0..1023 of w_att1, [k][n] f32) -> w1eT bf16 [n][k]
// grid (16,16) block 256
__global__ void k_transpose_w1e(const float* __restrict__ w_att1,
                                unsigned short* __restrict__ w1eT) {
  __shared__ float tile[64][65];
  const int k0 = blockIdx.y * 64, n0 = blockIdx.x * 64;
  const int c = threadIdx.x & 63, r0 = threadIdx.x >> 6;
#pragma unroll
  for (int i = 0; i < 16; i++) {
    int r = i * 4 + r0;
    tile[r][c] = w_att1[(size_t)(k0 + r) * ATTNSZ + n0 + c];
  }
  __syncthreads();
#pragma unroll
  for (int i = 0; i < 16; i++) {
    int r = i * 4 + r0;
    w1eT[(size_t)(n0 + r) * HID + k0 + c] = f2bf(tile[c][r]);
  }
}

// ---------------------------------------------------------------------------
// K1: dec_term[b][n] = sum_k state[1][b][k] * w_att1[HID+k][n]
// grid (4,16) block 256 ; 4 batches per block
__global__ void k_dec_term(const float* __restrict__ state,
                           const float* __restrict__ w_att1,
                           float* __restrict__ dec_term) {
  const int n = blockIdx.x * 256 + threadIdx.x;
  const int b0 = blockIdx.y * 4;
  const float* dec = state + (size_t)HID * BATCH;  // state[1]
  const float* w1d = w_att1 + (size_t)HID * ATTNSZ;
  float a0 = 0.f, a1 = 0.f, a2 = 0.f, a3 = 0.f;
  for (int k = 0; k < HID; k++) {
    float w = w1d[(size_t)k * ATTNSZ + n];
    a0 += dec[(b0 + 0) * HID + k] * w;
    a1 += dec[(b0 + 1) * HID + k] * w;
    a2 += dec[(b0 + 2) * HID + k] * w;
    a3 += dec[(b0 + 3) * HID + k] * w;
  }
  dec_term[(b0 + 0) * ATTNSZ + n] = a0;
  dec_term[(b0 + 1) * ATTNSZ + n] = a1;
  dec_term[(b0 + 2) * ATTNSZ + n] = a2;
  dec_term[(b0 + 3) * ATTNSZ + n] = a3;
}

// ---------------------------------------------------------------------------
// K2: attention GEMM + tanh + dot(w_att2) -> atomic e[m]
// G[m][n] = sum_k enc[m][k]*w1e[k][n];  e[m] += sum_n tanh(G+dec_term)*w2[n]
// tile 128M x 256N, BK=32, 512 threads (8 waves, 2x4 wave grid)
// grid (4, 512): n fast-varying so same-M blocks co-resident (L3 reuse of A)
__global__ __launch_bounds__(512) void k_attn_gemm(
    const float* __restrict__ enc, const unsigned short* __restrict__ w1eT,
    const float* __restrict__ dec_term, const float* __restrict__ w_att2,
    float* __restrict__ e) {
  __shared__ __align__(16) unsigned short As[128 * 32];  // [m][k] bf16
  __shared__ __align__(16) unsigned short Bs[256 * 32];  // [n][k] bf16

  const int tid = threadIdx.x;
  const int lane = tid & 63;
  const int wv = tid >> 6;   // 0..7
  const int wr = wv >> 2;    // 0..1 : 64-row group
  const int wc = wv & 3;     // 0..3 : 64-col group
  const int quad = lane >> 4;
  const int l15 = lane & 15;
  const int Mbase = blockIdx.y * 128;
  const int Nbase = blockIdx.x * 256;

  f32x4 acc[4][4] = {};

  // A staging: slot s in {tid, tid+512}: m = s>>3, f4 = s&7
  const float* aptr0 = enc + (size_t)(Mbase + (tid >> 3)) * HID + (tid & 7) * 4;
  const float* aptr1 = aptr0 + (size_t)64 * HID;
  unsigned short* As_w = As + tid * 4;             // = m*32 + f4*4
  // B staging: two rows per thread: n = tid>>2 and n+128; kpart = tid&3
  // LDS dest = wave-uniform base + lane*16B for each call.
  const unsigned short* bptr0 =
      w1eT + (size_t)(Nbase + (tid >> 2)) * HID + (tid & 3) * 8;
  const unsigned short* bptr1 = bptr0 + (size_t)128 * HID;
  unsigned short* Bs_w0 = Bs + tid * 8;            // rows [0,128): n*32+kpart*8
  unsigned short* Bs_w1 = Bs_w0 + 512 * 8;         // rows [128,256)

  for (int ks = 0; ks < 32; ks++) {
    __syncthreads();
    __builtin_amdgcn_global_load_lds(
        (const __attribute__((address_space(1))) unsigned int*)(bptr0 + ks * 32),
        (__attribute__((address_space(3))) unsigned int*)Bs_w0, 16, 0, 0);
    __builtin_amdgcn_global_load_lds(
        (const __attribute__((address_space(1))) unsigned int*)(bptr1 + ks * 32),
        (__attribute__((address_space(3))) unsigned int*)Bs_w1, 16, 0, 0);
    f32x4 a0 = *(const f32x4*)(aptr0 + ks * 32);
    f32x4 a1 = *(const f32x4*)(aptr1 + ks * 32);
    u16x4 c0, c1;
    c0.x = f2bf(a0.x); c0.y = f2bf(a0.y); c0.z = f2bf(a0.z); c0.w = f2bf(a0.w);
    c1.x = f2bf(a1.x); c1.y = f2bf(a1.y); c1.z = f2bf(a1.z); c1.w = f2bf(a1.w);
    *(u16x4*)As_w = c0;
    *(u16x4*)(As_w + 64 * 32) = c1;
    __syncthreads();

    s16x8 af[4], bfr[4];
#pragma unroll
    for (int it = 0; it < 4; it++)
      af[it] = *(const s16x8*)(As + (wr * 64 + it * 16 + l15) * 32 + quad * 8);
#pragma unroll
    for (int jt = 0; jt < 4; jt++)
      bfr[jt] = *(const s16x8*)(Bs + (wc * 64 + jt * 16 + l15) * 32 + quad * 8);
#pragma unroll
    for (int it = 0; it < 4; it++)
#pragma unroll
      for (int jt = 0; jt < 4; jt++)
        acc[it][jt] = __builtin_amdgcn_mfma_f32_16x16x32_bf16(
            af[it], bfr[jt], acc[it][jt], 0, 0, 0);
  }

  // epilogue: + dec_term, tanh, * w2, reduce over n, atomic into e
  float w2v[4];
  int ncol[4];
#pragma unroll
  for (int jt = 0; jt < 4; jt++) {
    ncol[jt] = Nbase + wc * 64 + jt * 16 + l15;
    w2v[jt] = w_att2[ncol[jt]];
  }
#pragma unroll
  for (int it = 0; it < 4; it++) {
#pragma unroll
    for (int j = 0; j < 4; j++) {
      const int b = it * 16 + quad * 4 + j;  // batch = row & 63 (blocks 128-aligned)
      float s = 0.f;
#pragma unroll
      for (int jt = 0; jt < 4; jt++) {
        float g = acc[it][jt][j] + dec_term[b * ATTNSZ + ncol[jt]];
        s += fast_tanh(g) * w2v[jt];
      }
      s += __shfl_xor(s, 1);
      s += __shfl_xor(s, 2);
      s += __shfl_xor(s, 4);
      s += __shfl_xor(s, 8);
      if (l15 == 0) atomicAdd(&e[Mbase + wr * 64 + b], s);
    }
  }
}

// ---------------------------------------------------------------------------
// K3: softmax over t (axis 0) per batch; e,alpha layout [t*64+b]
// grid 64, block 256
__global__ void k_softmax(const float* __restrict__ e,
                          float* __restrict__ alpha) {
  __shared__ float red[256];
  const int b = blockIdx.x, tid = threadIdx.x;
  float m = -1e30f;
  for (int t = tid; t < MAXLEN; t += 256) m = fmaxf(m, e[t * BATCH + b]);
  red[tid] = m;
  __syncthreads();
  for (int s = 128; s > 0; s >>= 1) {
    if (tid < s) red[tid] = fmaxf(red[tid], red[tid + s]);
    __syncthreads();
  }
  m = red[0];
  __syncthreads();
  float sum = 0.f;
  for (int t = tid; t < MAXLEN; t += 256) {
    float ex = __expf(e[t * BATCH + b] - m);
    alpha[t * BATCH + b] = ex;
    sum += ex;
  }
  red[tid] = sum;
  __syncthreads();
  for (int s = 128; s > 0; s >>= 1) {
    if (tid < s) red[tid] += red[tid + s];
    __syncthreads();
  }
  float inv = 1.f / red[0];
  for (int t = tid; t < MAXLEN; t += 256) alpha[t * BATCH + b] *= inv;
}

// ---------------------------------------------------------------------------
// K4: context partials: cpart[tc][b][h] = sum_{t in chunk} alpha[t,b]*enc[t,b,h]
// grid (8, 64) block 256; each thread a float4 of h
__global__ void k_context(const float* __restrict__ enc,
                          const float* __restrict__ alpha,
                          float* __restrict__ cpart) {
  const int tc = blockIdx.x, b = blockIdx.y, tid = threadIdx.x;
  f32x4 acc = {0.f, 0.f, 0.f, 0.f};
#pragma unroll 4
  for (int t = tc * 128; t < tc * 128 + 128; t++) {
    float a = alpha[t * BATCH + b];
    f32x4 v = *(const f32x4*)(enc + (size_t)(t * BATCH + b) * HID + tid * 4);
    acc.x += a * v.x; acc.y += a * v.y; acc.z += a * v.z; acc.w += a * v.w;
  }
  *(f32x4*)(cpart + (size_t)(tc * BATCH + b) * HID + tid * 4) = acc;
}

// ---------------------------------------------------------------------------
// K4b: x[b] = [ embedding[cur[b]] (512) , sum_p cpart[p][b] (1024) ]
// grid 64, block 256
__global__ void k_build_x(const int* __restrict__ cur,
                          const float* __restrict__ embedding,
                          const float* __restrict__ cpart,
                          float* __restrict__ x) {
  const int b = blockIdx.x, tid = threadIdx.x;
  const int row = cur[b];
  if (tid < 128) {
    f32x4 v = *(const f32x4*)(embedding + (size_t)row * EMBED + tid * 4);
    *(f32x4*)(x + (size_t)b * 1536 + tid * 4) = v;
  }
  f32x4 s = {0.f, 0.f, 0.f, 0.f};
#pragma unroll
  for (int p = 0; p < 8; p++) {
    f32x4 v = *(const f32x4*)(cpart + (size_t)(p * BATCH + b) * HID + tid * 4);
    s.x += v.x; s.y += v.y; s.z += v.z; s.w += v.w;
  }
  *(f32x4*)(x + (size_t)b * 1536 + 512 + tid * 4) = s;
}

// ---------------------------------------------------------------------------
// K5: skinny GEMM: out[b][j] = sum_k A[b][k]*W[j][k] + bias[j]
// A: (64,K), W: (J,K) row-major. block 256 (4 waves, 8 j-rows/wave),
// grid ceil(J/32). A^T chunk staged in LDS [k][b] pad 65; W via scalar loads.
__global__ __launch_bounds__(256) void k_gemmT(
    const float* __restrict__ A, const float* __restrict__ W,
    const float* __restrict__ bias, float* __restrict__ out, int K, int J) {
  __shared__ float At[128 * 65];
  const int tid = threadIdx.x;
  const int lane = tid & 63;
  const int wv = __builtin_amdgcn_readfirstlane(tid >> 6);
  const int j0 = blockIdx.x * 32 + wv * 8;
  const float* wb[8];
#pragma unroll
  for (int jj = 0; jj < 8; jj++) {
    int j = j0 + jj;
    if (j > J - 1) j = J - 1;
    wb[jj] = W + (size_t)j * K;
  }
  float acc[8] = {};
  for (int kc = 0; kc < K; kc += 128) {
    __syncthreads();
#pragma unroll
    for (int i = 0; i < 8; i++) {
      int s = i * 256 + tid;
      int b = s >> 5, f4 = s & 31;
      f32x4 v = *(const f32x4*)(A + (size_t)b * K + kc + f4 * 4);
      At[(f4 * 4 + 0) * 65 + b] = v.x;
      At[(f4 * 4 + 1) * 65 + b] = v.y;
      At[(f4 * 4 + 2) * 65 + b] = v.z;
      At[(f4 * 4 + 3) * 65 + b] = v.w;
    }
    __syncthreads();
    for (int k = 0; k < 128; k += 4) {
      float a0 = At[(k + 0) * 65 + lane];
      float a1 = At[(k + 1) * 65 + lane];
      float a2 = At[(k + 2) * 65 + lane];
      float a3 = At[(k + 3) * 65 + lane];
#pragma unroll
      for (int jj = 0; jj < 8; jj++) {
        const float* wr = wb[jj] + kc + k;
        acc[jj] += wr[0] * a0 + wr[1] * a1 + wr[2] * a2 + wr[3] * a3;
      }
    }
  }
#pragma unroll
  for (int jj = 0; jj < 8; jj++) {
    int j = j0 + jj;
    if (j < J) out[(size_t)lane * J + j] = acc[jj] + bias[j];
  }
}

// ---------------------------------------------------------------------------
// K6: GRU gate fusion. gi,gh: (64,3072); hprev: (64,1024)
// grid 256, block 256
__global__ void k_gru_gate(const float* __restrict__ gi,
                           const float* __restrict__ gh,
                           const float* __restrict__ hprev,
                           float* __restrict__ h_ws,
                           float* __restrict__ h_out) {
  const int idx = blockIdx.x * 256 + threadIdx.x;  // b*1024 + h
  const int b = idx >> 10, h = idx & 1023;
  const float* gib = gi + (size_t)b * GATE3;
  const float* ghb = gh + (size_t)b * GATE3;
  float r = fast_sigmoid(gib[h] + ghb[h]);
  float z = fast_sigmoid(gib[HID + h] + ghb[HID + h]);
  float n = fast_tanh(gib[2 * HID + h] + r * ghb[2 * HID + h]);
  float out = (1.f - z) * n + z * hprev[idx];
  h_ws[idx] = out;
  h_out[idx] = out;
}

// ---------------------------------------------------------------------------
extern "C" void kernel_launch(void* const* d_in, const int* in_sizes, int n_in,
                              void* d_out, int out_size, void* d_ws,
                              size_t ws_size, hipStream_t stream) {
  const int* cur = (const int*)d_in[0];
  const float* state = (const float*)d_in[1];
  const float* enc = (const float*)d_in[2];
  const float* embedding = (const float*)d_in[3];
  const float* w_att1 = (const float*)d_in[4];
  const float* w_att2 = (const float*)d_in[5];
  const float* w_ih0 = (const float*)d_in[6];
  const float* w_hh0 = (const float*)d_in[7];
  const float* b_ih0 = (const float*)d_in[8];
  const float* b_hh0 = (const float*)d_in[9];
  const float* w_ih1 = (const float*)d_in[10];
  const float* w_hh1 = (const float*)d_in[11];
  const float* b_ih1 = (const float*)d_in[12];
  const float* b_hh1 = (const float*)d_in[13];
  const float* w_out = (const float*)d_in[14];
  const float* b_out = (const float*)d_in[15];
  float* out = (float*)d_out;

  char* ws = (char*)d_ws;
  size_t off = 0;
  auto alloc = [&](size_t bytes) {
    void* p = ws + off;
    off += (bytes + 255) & ~(size_t)255;
    return p;
  };
  unsigned short* w1eT = (unsigned short*)alloc((size_t)ATTNSZ * HID * 2);
  float* dec_term = (float*)alloc((size_t)BATCH * ATTNSZ * 4);
  float* e = (float*)alloc((size_t)MTOT * 4);
  float* alpha = (float*)alloc((size_t)MTOT * 4);
  float* cpart = (float*)alloc((size_t)8 * BATCH * HID * 4);
  float* x = (float*)alloc((size_t)BATCH * 1536 * 4);
  float* gi0 = (float*)alloc((size_t)BATCH * GATE3 * 4);
  float* gh0 = (float*)alloc((size_t)BATCH * GATE3 * 4);
  float* gi1 = (float*)alloc((size_t)BATCH * GATE3 * 4);
  float* gh1 = (float*)alloc((size_t)BATCH * GATE3 * 4);
  float* h0 = (float*)alloc((size_t)BATCH * HID * 4);
  float* h1 = (float*)alloc((size_t)BATCH * HID * 4);
  (void)ws_size;

  float* out_state = out + (size_t)BATCH * VOCABSZ;

  hipMemsetAsync(e, 0, (size_t)MTOT * 4, stream);
  k_transpose_w1e<<<dim3(16, 16), 256, 0, stream>>>(w_att1, w1eT);
  k_dec_term<<<dim3(4, 16), 256, 0, stream>>>(state, w_att1, dec_term);
  k_attn_gemm<<<dim3(4, 512), 512, 0, stream>>>(enc, w1eT, dec_term, w_att2, e);
  k_softmax<<<64, 256, 0, stream>>>(e, alpha);
  k_context<<<dim3(8, 64), 256, 0, stream>>>(enc, alpha, cpart);
  k_build_x<<<64, 256, 0, stream>>>(cur, embedding, cpart, x);
  k_gemmT<<<96, 256, 0, stream>>>(x, w_ih0, b_ih0, gi0, 1536, GATE3);
  k_gemmT<<<96, 256, 0, stream>>>(state, w_hh0, b_hh0, gh0, HID, GATE3);
  k_gru_gate<<<256, 256, 0, stream>>>(gi0, gh0, state, h0, out_state);
  k_gemmT<<<96, 256, 0, stream>>>(h0, w_ih1, b_ih1, gi1, HID, GATE3);
  k_gemmT<<<96, 256, 0, stream>>>(state + (size_t)BATCH * HID, w_hh1, b_hh1,
                                  gh1, HID, GATE3);
  k_gru_gate<<<256, 256, 0, stream>>>(gi1, gh1, state + (size_t)BATCH * HID, h1,
                                      out_state + (size_t)BATCH * HID);
  k_gemmT<<<(VOCABSZ + 31) / 32, 256, 0, stream>>>(h1, w_out, b_out, out, HID,
                                                   VOCABSZ);
}